// Round 1
// 157.321 us; speedup vs baseline: 1.1717x; 1.1717x over previous
//
#include <hip/hip_runtime.h>

// SoftAttention: B=4, Q=64, S=1024, H=512, fp32.
// out = [context (B*Q*H)] ++ [weights (B*Q*S)]
// ws layout: qp [256*512] @0; kp [4096*512] @+512KB; part aliases kp;
//            Bhi/Blo (bf16 hi/lo of Wk,Wq, granule-major) @+8.5MB (1MB each).
// NOTE: proj writes 2*(X@W + b) — score uses only exp(2*(q+k)); be cancels.
//
// R1 change: proj GEMM moved from fp32 VALU (59.4us, MfmaUtil=0) to bf16 MFMA
// with 3-product hi/lo split (hi=rtn_bf16(x), lo=rtn_bf16(x-hi); drop lo*lo
// ~2^-16 rel => ~1e-5 abs error on qp/kp). W pre-converted by convert_w into
// granule-major layout so GEMM B staging is linear/coalesced and LDS fragment
// reads are 256B-contiguous (conflict-free). X converted inline in staging.

constexpr int kB = 4;
constexpr int kQ = 64;
constexpr int kS = 1024;
constexpr int kH = 512;

typedef short bf16x8 __attribute__((ext_vector_type(8)));
typedef float f32x4 __attribute__((ext_vector_type(4)));

__device__ __forceinline__ unsigned bf16rtn_bits(float x) {
  unsigned u = __float_as_uint(x);
  u += 0x7FFFu + ((u >> 16) & 1u);
  return u;  // hi bf16 = u>>16; its f32 bits = u & 0xFFFF0000
}

// ---------------------------------------------------------------------------
// W converter: Wk/Wq [512][512] fp32 -> bf16 hi/lo, granule-major:
// granule gid = ((mat*8 + ct)*16 + kt)*256 + (g*64 + c), holding
// W[kt*32 + g*8 + j][ct*64 + c] for j=0..7 (8 contiguous k per 16B granule).
// 65536 granules -> 256 blocks x 256 thr.
// ---------------------------------------------------------------------------
__global__ __launch_bounds__(256) void convert_w(
    const float* __restrict__ Wk, const float* __restrict__ Wq,
    unsigned short* __restrict__ Bhi, unsigned short* __restrict__ Blo) {
  const int gid = blockIdx.x * 256 + threadIdx.x;
  const int c = gid & 63;
  const int g = (gid >> 6) & 3;
  const int kt = (gid >> 8) & 15;
  const int ct = (gid >> 12) & 7;
  const int mat = gid >> 15;
  const float* W = mat ? Wq : Wk;
  const float* src = W + (size_t)(kt * 32 + g * 8) * kH + ct * 64 + c;
  bf16x8 hv, lv;
#pragma unroll
  for (int j = 0; j < 8; j++) {
    float x = src[(size_t)j * kH];
    unsigned u = bf16rtn_bits(x);
    float hf = __uint_as_float(u & 0xFFFF0000u);
    unsigned v = bf16rtn_bits(x - hf);
    hv[j] = (short)(u >> 16);
    lv[j] = (short)(v >> 16);
  }
  *(bf16x8*)(Bhi + (size_t)gid * 8) = hv;
  *(bf16x8*)(Blo + (size_t)gid * 8) = lv;
}

// ---------------------------------------------------------------------------
// Projection via MFMA: Y = 2*(X[M,512] @ W[512,512] + bias), bf16 3-product.
// 64x64 tile, 256 thr = 4 waves (2x2), each wave 32x32 = 2x2 16x16 frags.
// BK=32, double-buffered LDS (32KB), single barrier per K-step.
// LDS layout per buffer: 256 granules of 16B, slot = g*64 + r (granule-major)
// -> fragment ds_read_b128 is 256B-contiguous per 16-lane group.
// grid = (8 col-tiles, 68 row-tiles: 64 kp + 4 qp)
// ---------------------------------------------------------------------------
__global__ __launch_bounds__(256) void proj_mfma(
    const float* __restrict__ key_, const float* __restrict__ query,
    const unsigned short* __restrict__ Bhi, const unsigned short* __restrict__ Blo,
    const float* __restrict__ bk, const float* __restrict__ bq,
    float* __restrict__ kp, float* __restrict__ qp) {
  __shared__ __align__(16) unsigned short AhiL[2][2048];
  __shared__ __align__(16) unsigned short AloL[2][2048];
  __shared__ __align__(16) unsigned short BhiL[2][2048];
  __shared__ __align__(16) unsigned short BloL[2][2048];

  const int ct = blockIdx.x;
  int rt = blockIdx.y;
  const float* X;
  const float* bias;
  float* Y;
  int mat;
  if (rt < 64) {
    X = key_ + (size_t)rt * 64 * kH; bias = bk; Y = kp + (size_t)rt * 64 * kH; mat = 0;
  } else {
    rt -= 64;
    X = query + (size_t)rt * 64 * kH; bias = bq; Y = qp + (size_t)rt * 64 * kH; mat = 1;
  }

  const int t = threadIdx.x;
  // A staging: thread t loads rows ar = t&63, k-granule ag = t>>6 (8 fp32).
  const int ar = t & 63, ag = t >> 6;
  const float* aptr = X + (size_t)ar * kH + ag * 8;
  // B staging: linear granule t of this (mat,ct) panel.
  const unsigned short* bht = Bhi + ((size_t)(mat * 8 + ct) * 16) * 2048 + t * 8;
  const unsigned short* blt = Blo + ((size_t)(mat * 8 + ct) * 16) * 2048 + t * 8;

  float4 pa0, pa1;
  uint4 pbh, pbl;
  auto gload = [&](int kt) {
    const float* p = aptr + kt * 32;
    pa0 = *(const float4*)p;
    pa1 = *(const float4*)(p + 4);
    pbh = *(const uint4*)(bht + (size_t)kt * 2048);
    pbl = *(const uint4*)(blt + (size_t)kt * 2048);
  };
  auto cwrite = [&](int buf) {
    bf16x8 hv, lv;
#define CVT1(x, e)                                          \
  {                                                         \
    unsigned u = bf16rtn_bits(x);                           \
    float hf = __uint_as_float(u & 0xFFFF0000u);            \
    unsigned v = bf16rtn_bits((x) - hf);                    \
    hv[e] = (short)(u >> 16);                               \
    lv[e] = (short)(v >> 16);                               \
  }
    CVT1(pa0.x, 0) CVT1(pa0.y, 1) CVT1(pa0.z, 2) CVT1(pa0.w, 3)
    CVT1(pa1.x, 4) CVT1(pa1.y, 5) CVT1(pa1.z, 6) CVT1(pa1.w, 7)
#undef CVT1
    // granule slot for (g=ag, r=ar) is ag*64+ar == t -> contiguous writes.
    *(bf16x8*)&AhiL[buf][t * 8] = hv;
    *(bf16x8*)&AloL[buf][t * 8] = lv;
    *(uint4*)&BhiL[buf][t * 8] = pbh;
    *(uint4*)&BloL[buf][t * 8] = pbl;
  };

  // Fragment addressing. lane l: A row = l&15, k-granule = l>>4 (8 contig k);
  // B col = l&15, same k-granule. C/D: col = l&15, row = (l>>4)*4 + jj.
  const int l = t & 63, lg = l >> 4, lr = l & 15;
  const int wv = t >> 6, wm = wv >> 1, wn = wv & 1;
  const int oa0 = (lg * 64 + (2 * wm) * 16 + lr) * 8;  // halves; +128 for frag i=1
  const int ob0 = (lg * 64 + (2 * wn) * 16 + lr) * 8;

  f32x4 acc00 = {0.f, 0.f, 0.f, 0.f};
  f32x4 acc01 = acc00, acc10 = acc00, acc11 = acc00;

  gload(0);
  cwrite(0);
  __syncthreads();

#pragma unroll 2
  for (int kt = 0; kt < 16; kt++) {
    if (kt < 15) gload(kt + 1);

    const unsigned short* Ah = AhiL[kt & 1];
    const unsigned short* Al = AloL[kt & 1];
    const unsigned short* Bh = BhiL[kt & 1];
    const unsigned short* Bl = BloL[kt & 1];
    bf16x8 ah0 = *(const bf16x8*)(Ah + oa0);
    bf16x8 ah1 = *(const bf16x8*)(Ah + oa0 + 128);
    bf16x8 al0 = *(const bf16x8*)(Al + oa0);
    bf16x8 al1 = *(const bf16x8*)(Al + oa0 + 128);
    bf16x8 bh0 = *(const bf16x8*)(Bh + ob0);
    bf16x8 bh1 = *(const bf16x8*)(Bh + ob0 + 128);
    bf16x8 bl0 = *(const bf16x8*)(Bl + ob0);
    bf16x8 bl1 = *(const bf16x8*)(Bl + ob0 + 128);

    // 3-product split: hi*hi + lo*hi + hi*lo (lo*lo dropped, ~2^-16 rel).
    acc00 = __builtin_amdgcn_mfma_f32_16x16x32_bf16(ah0, bh0, acc00, 0, 0, 0);
    acc01 = __builtin_amdgcn_mfma_f32_16x16x32_bf16(ah0, bh1, acc01, 0, 0, 0);
    acc10 = __builtin_amdgcn_mfma_f32_16x16x32_bf16(ah1, bh0, acc10, 0, 0, 0);
    acc11 = __builtin_amdgcn_mfma_f32_16x16x32_bf16(ah1, bh1, acc11, 0, 0, 0);
    acc00 = __builtin_amdgcn_mfma_f32_16x16x32_bf16(al0, bh0, acc00, 0, 0, 0);
    acc01 = __builtin_amdgcn_mfma_f32_16x16x32_bf16(al0, bh1, acc01, 0, 0, 0);
    acc10 = __builtin_amdgcn_mfma_f32_16x16x32_bf16(al1, bh0, acc10, 0, 0, 0);
    acc11 = __builtin_amdgcn_mfma_f32_16x16x32_bf16(al1, bh1, acc11, 0, 0, 0);
    acc00 = __builtin_amdgcn_mfma_f32_16x16x32_bf16(ah0, bl0, acc00, 0, 0, 0);
    acc01 = __builtin_amdgcn_mfma_f32_16x16x32_bf16(ah0, bl1, acc01, 0, 0, 0);
    acc10 = __builtin_amdgcn_mfma_f32_16x16x32_bf16(ah1, bl0, acc10, 0, 0, 0);
    acc11 = __builtin_amdgcn_mfma_f32_16x16x32_bf16(ah1, bl1, acc11, 0, 0, 0);

    if (kt < 15) {
      cwrite((kt + 1) & 1);  // targets other buffer; prior readers crossed last barrier
      __syncthreads();
    }
  }

  // Epilogue: Y = 2*(acc + bias). C/D: col = lr, row = lg*4 + jj (+16 per m-frag).
  const int n0 = ct * 64;
  const int col0 = n0 + (2 * wn) * 16 + lr;
  const float b0 = bias[col0];
  const float b1 = bias[col0 + 16];
  const int row0 = (2 * wm) * 16 + lg * 4;
#pragma unroll
  for (int jj = 0; jj < 4; jj++) {
    float* y = Y + (size_t)(row0 + jj) * kH;
    y[col0]      = 2.f * (acc00[jj] + b0);
    y[col0 + 16] = 2.f * (acc01[jj] + b1);
    float* y2 = y + (size_t)16 * kH;
    y2[col0]      = 2.f * (acc10[jj] + b0);
    y2[col0 + 16] = 2.f * (acc11[jj] + b1);
  }
}

// ---------------------------------------------------------------------------
// Scores (raw) -> sout[bq][s].  qp/kp hold 2*(proj); be cancels in softmax.
// tanh(x) = 1 - 2*rcp(1+exp(2x));  sum we*tanh = sum_we + sum (-2*we)*rcp(...)
// grid = 1024 (b x 16 q-tiles x 16 s-chunks), 256 thr = 4 waves, 16 s/wave.
// ---------------------------------------------------------------------------
__global__ __launch_bounds__(256) void score_kernel(
    const float* __restrict__ qp, const float* __restrict__ kp,
    const float* __restrict__ we, float* __restrict__ sout) {
  const int bx = blockIdx.x;
  const int b = bx >> 8, qt = (bx >> 4) & 15, st = bx & 15;
  const int t = threadIdx.x, wave = t >> 6, lane = t & 63;

  const float4* we4 = (const float4*)(we + lane * 8);
  float4 w0 = we4[0], w1 = we4[1];
  float wsum = w0.x + w0.y + w0.z + w0.w + w1.x + w1.y + w1.z + w1.w;
#pragma unroll
  for (int off = 32; off; off >>= 1) wsum += __shfl_xor(wsum, off);
  // fold the -2 of tanh into the weights
  w0.x *= -2.f; w0.y *= -2.f; w0.z *= -2.f; w0.w *= -2.f;
  w1.x *= -2.f; w1.y *= -2.f; w1.z *= -2.f; w1.w *= -2.f;

  const int q0 = qt * 4;
  float4 qv[4][2];
#pragma unroll
  for (int i = 0; i < 4; i++) {
    const float4* q4 = (const float4*)(qp + (size_t)(b * kQ + q0 + i) * kH + lane * 8);
    qv[i][0] = q4[0]; qv[i][1] = q4[1];
  }

  const int sbase = st * 64 + wave * 16;
  const float* kbase = kp + ((size_t)b * kS + sbase) * kH + lane * 8;

  float4 k0 = *(const float4*)(kbase);
  float4 k1 = *(const float4*)(kbase + 4);

  for (int si = 0; si < 16; si++) {
    float4 n0, n1;
    if (si < 15) {
      const float* np = kbase + (size_t)(si + 1) * kH;
      n0 = *(const float4*)(np);
      n1 = *(const float4*)(np + 4);
    }
    float a[4];
#pragma unroll
    for (int i = 0; i < 4; i++) {
      float acc = 0.f, e;
      e = __expf(qv[i][0].x + k0.x); acc = fmaf(w0.x, __builtin_amdgcn_rcpf(1.f + e), acc);
      e = __expf(qv[i][0].y + k0.y); acc = fmaf(w0.y, __builtin_amdgcn_rcpf(1.f + e), acc);
      e = __expf(qv[i][0].z + k0.z); acc = fmaf(w0.z, __builtin_amdgcn_rcpf(1.f + e), acc);
      e = __expf(qv[i][0].w + k0.w); acc = fmaf(w0.w, __builtin_amdgcn_rcpf(1.f + e), acc);
      e = __expf(qv[i][1].x + k1.x); acc = fmaf(w1.x, __builtin_amdgcn_rcpf(1.f + e), acc);
      e = __expf(qv[i][1].y + k1.y); acc = fmaf(w1.y, __builtin_amdgcn_rcpf(1.f + e), acc);
      e = __expf(qv[i][1].z + k1.z); acc = fmaf(w1.z, __builtin_amdgcn_rcpf(1.f + e), acc);
      e = __expf(qv[i][1].w + k1.w); acc = fmaf(w1.w, __builtin_amdgcn_rcpf(1.f + e), acc);
      a[i] = acc;
    }
#pragma unroll
    for (int i = 0; i < 4; i++) {
#pragma unroll
      for (int off = 32; off; off >>= 1) a[i] += __shfl_xor(a[i], off);
    }
    if (lane == 0) {
      const int s = sbase + si;
#pragma unroll
      for (int i = 0; i < 4; i++)
        sout[(size_t)(b * kQ + q0 + i) * kS + s] = a[i] + wsum;
    }
    k0 = n0; k1 = n1;
  }
}

// ---------------------------------------------------------------------------
// Softmax in place on wout rows of 1024.  grid = 256 rows, 256 thr.
// ---------------------------------------------------------------------------
__global__ __launch_bounds__(256) void softmax_kernel(float* __restrict__ wout) {
  __shared__ float redm[4];
  __shared__ float reds[4];
  const int row = blockIdx.x;
  const int t = threadIdx.x, wave = t >> 6, lane = t & 63;
  float4* rp = (float4*)(wout + (size_t)row * kS);
  float4 v = rp[t];

  float m = fmaxf(fmaxf(v.x, v.y), fmaxf(v.z, v.w));
#pragma unroll
  for (int off = 32; off; off >>= 1) m = fmaxf(m, __shfl_xor(m, off));
  if (lane == 0) redm[wave] = m;
  __syncthreads();
  m = fmaxf(fmaxf(redm[0], redm[1]), fmaxf(redm[2], redm[3]));

  float4 e;
  e.x = __expf(v.x - m); e.y = __expf(v.y - m);
  e.z = __expf(v.z - m); e.w = __expf(v.w - m);
  float sum = e.x + e.y + e.z + e.w;
#pragma unroll
  for (int off = 32; off; off >>= 1) sum += __shfl_xor(sum, off);
  if (lane == 0) reds[wave] = sum;
  __syncthreads();
  sum = reds[0] + reds[1] + reds[2] + reds[3];
  float inv = 1.f / sum;
  e.x *= inv; e.y *= inv; e.z *= inv; e.w *= inv;
  rp[t] = e;
}

// ---------------------------------------------------------------------------
// Context partials: part[sc][bq][h] = sum_{s in chunk} w[bq][s] * value[b][s][h]
// grid = 256 (b x 2 h-chunks x 4 q-chunks x 8 s-chunks), 256 thr.
// ---------------------------------------------------------------------------
__global__ __launch_bounds__(256) void context_kernel(
    const float* __restrict__ wout, const float* __restrict__ value,
    float* __restrict__ part) {
  __shared__ __align__(16) float wt[128][16];
  const int bx = blockIdx.x;
  const int sc = bx & 7, qc = (bx >> 3) & 3, hc = (bx >> 5) & 1, b = bx >> 6;
  const int t = threadIdx.x;
  const int s0 = sc * 128, q0 = qc * 16;

  {
    const int q_l = t & 15;
    const int sseg = (t >> 4) * 8;
    const float4* p4 =
        (const float4*)(wout + (size_t)(b * kQ + q0 + q_l) * kS + s0 + sseg);
    float4 u0 = p4[0], u1 = p4[1];
    wt[sseg + 0][q_l] = u0.x; wt[sseg + 1][q_l] = u0.y;
    wt[sseg + 2][q_l] = u0.z; wt[sseg + 3][q_l] = u0.w;
    wt[sseg + 4][q_l] = u1.x; wt[sseg + 5][q_l] = u1.y;
    wt[sseg + 6][q_l] = u1.z; wt[sseg + 7][q_l] = u1.w;
  }
  __syncthreads();

  const int h = hc * 256 + t;
  const float* vb = value + ((size_t)b * kS + s0) * kH + h;
  float acc[16];
#pragma unroll
  for (int i = 0; i < 16; i++) acc[i] = 0.f;

#pragma unroll 4
  for (int s = 0; s < 128; s++) {
    float v = vb[(size_t)s * kH];
    const float4* wrow = (const float4*)&wt[s][0];
    float4 a0 = wrow[0], a1 = wrow[1], a2 = wrow[2], a3 = wrow[3];
    acc[0]  = fmaf(a0.x, v, acc[0]);  acc[1]  = fmaf(a0.y, v, acc[1]);
    acc[2]  = fmaf(a0.z, v, acc[2]);  acc[3]  = fmaf(a0.w, v, acc[3]);
    acc[4]  = fmaf(a1.x, v, acc[4]);  acc[5]  = fmaf(a1.y, v, acc[5]);
    acc[6]  = fmaf(a1.z, v, acc[6]);  acc[7]  = fmaf(a1.w, v, acc[7]);
    acc[8]  = fmaf(a2.x, v, acc[8]);  acc[9]  = fmaf(a2.y, v, acc[9]);
    acc[10] = fmaf(a2.z, v, acc[10]); acc[11] = fmaf(a2.w, v, acc[11]);
    acc[12] = fmaf(a3.x, v, acc[12]); acc[13] = fmaf(a3.y, v, acc[13]);
    acc[14] = fmaf(a3.z, v, acc[14]); acc[15] = fmaf(a3.w, v, acc[15]);
  }

  float* pp = part + (size_t)sc * kB * kQ * kH;
#pragma unroll
  for (int i = 0; i < 16; i++)
    pp[(size_t)(b * kQ + q0 + i) * kH + h] = acc[i];
}

// ctx[i] = sum over 8 s-chunk partials
__global__ __launch_bounds__(256) void reduce_kernel(
    const float* __restrict__ part, float* __restrict__ ctx) {
  const int i = blockIdx.x * 256 + threadIdx.x;
  float4 a = {0, 0, 0, 0};
#pragma unroll
  for (int p = 0; p < 8; p++) {
    float4 v = ((const float4*)(part + (size_t)p * kB * kQ * kH))[i];
    a.x += v.x; a.y += v.y; a.z += v.z; a.w += v.w;
  }
  ((float4*)ctx)[i] = a;
}

extern "C" void kernel_launch(void* const* d_in, const int* in_sizes, int n_in,
                              void* d_out, int out_size, void* d_ws,
                              size_t ws_size, hipStream_t stream) {
  const float* query = (const float*)d_in[0];
  const float* key_  = (const float*)d_in[1];
  const float* value = (const float*)d_in[2];
  const float* Wq    = (const float*)d_in[3];
  const float* bq    = (const float*)d_in[4];
  const float* Wk    = (const float*)d_in[5];
  const float* bk    = (const float*)d_in[6];
  const float* we    = (const float*)d_in[7];
  // be (d_in[8]) cancels in softmax.

  float* ctx  = (float*)d_out;                         // [256*512]
  float* wout = (float*)d_out + (size_t)kB * kQ * kH;  // [256*1024]

  float* qp   = (float*)d_ws;                          // 512 KB
  float* kp   = qp + (size_t)kB * kQ * kH;             // 8 MB
  float* part = kp;                                    // aliases kp (dead after score)
  unsigned short* Bhi =
      (unsigned short*)((char*)d_ws + (size_t)(kB * kQ * kH + kB * kS * kH) * 4);  // +8.5MB, 1MB
  unsigned short* Blo = Bhi + (size_t)2 * 8 * 16 * 256 * 8;                        // +1MB

  convert_w<<<256, 256, 0, stream>>>(Wk, Wq, Bhi, Blo);
  proj_mfma<<<dim3(8, 68), 256, 0, stream>>>(key_, query, Bhi, Blo, bk, bq, kp, qp);
  score_kernel<<<1024, 256, 0, stream>>>(qp, kp, we, wout);
  softmax_kernel<<<kB * kQ, 256, 0, stream>>>(wout);
  context_kernel<<<256, 256, 0, stream>>>(wout, value, part);
  reduce_kernel<<<kB * kQ * kH / 4 / 256, 256, 0, stream>>>(part, ctx);
}

// Round 2
// 150.102 us; speedup vs baseline: 1.2280x; 1.0481x over previous
//
#include <hip/hip_runtime.h>

// SoftAttention: B=4, Q=64, S=1024, H=512, fp32.
// out = [context (B*Q*H)] ++ [weights (B*Q*S)]
// ws layout: Eq [256*512] @0; Ek [4096*512] @+512KB; part aliases Ek;
//            Bhi/Blo (bf16 hi/lo of Wk,Wq, granule-major) @+8.5MB (1MB each).
//
// R1: proj on MFMA via bf16 3-product hi/lo split (59.4us -> ~?us, MfmaUtil>0).
// R2: score exp-factoring: proj epilogue writes Eq=exp(2(q+b)), Ek=exp(2(k+b));
//     score inner = w-pairs * rcp(1+Eq*Ek) with lane=s transposed layout
//     (no per-element exp, half the rcps, zero shuffle reduces).
//     tanh(x) = 1 - 2/(1+exp(2x)); sum we*tanh = wsum + sum(-2we)/(1+Eq*Ek);
//     be cancels in softmax.

constexpr int kB = 4;
constexpr int kQ = 64;
constexpr int kS = 1024;
constexpr int kH = 512;

typedef short bf16x8 __attribute__((ext_vector_type(8)));
typedef float f32x4 __attribute__((ext_vector_type(4)));

__device__ __forceinline__ unsigned bf16rtn_bits(float x) {
  unsigned u = __float_as_uint(x);
  u += 0x7FFFu + ((u >> 16) & 1u);
  return u;  // hi bf16 = u>>16; its f32 bits = u & 0xFFFF0000
}

// ---------------------------------------------------------------------------
// W converter: Wk/Wq [512][512] fp32 -> bf16 hi/lo, granule-major:
// granule gid = ((mat*8 + ct)*16 + kt)*256 + (g*64 + c), holding
// W[kt*32 + g*8 + j][ct*64 + c] for j=0..7 (8 contiguous k per 16B granule).
// ---------------------------------------------------------------------------
__global__ __launch_bounds__(256) void convert_w(
    const float* __restrict__ Wk, const float* __restrict__ Wq,
    unsigned short* __restrict__ Bhi, unsigned short* __restrict__ Blo) {
  const int gid = blockIdx.x * 256 + threadIdx.x;
  const int c = gid & 63;
  const int g = (gid >> 6) & 3;
  const int kt = (gid >> 8) & 15;
  const int ct = (gid >> 12) & 7;
  const int mat = gid >> 15;
  const float* W = mat ? Wq : Wk;
  const float* src = W + (size_t)(kt * 32 + g * 8) * kH + ct * 64 + c;
  bf16x8 hv, lv;
#pragma unroll
  for (int j = 0; j < 8; j++) {
    float x = src[(size_t)j * kH];
    unsigned u = bf16rtn_bits(x);
    float hf = __uint_as_float(u & 0xFFFF0000u);
    unsigned v = bf16rtn_bits(x - hf);
    hv[j] = (short)(u >> 16);
    lv[j] = (short)(v >> 16);
  }
  *(bf16x8*)(Bhi + (size_t)gid * 8) = hv;
  *(bf16x8*)(Blo + (size_t)gid * 8) = lv;
}

// ---------------------------------------------------------------------------
// Projection via MFMA: E = exp(2*(X[M,512] @ W[512,512] + bias)), bf16
// 3-product split. 64x64 tile, 256 thr = 4 waves (2x2), wave = 2x2 16x16 frags.
// BK=32, double-buffered LDS, single barrier per K-step.
// grid = (8 col-tiles, 68 row-tiles: 64 Ek + 4 Eq)
// ---------------------------------------------------------------------------
__global__ __launch_bounds__(256) void proj_mfma(
    const float* __restrict__ key_, const float* __restrict__ query,
    const unsigned short* __restrict__ Bhi, const unsigned short* __restrict__ Blo,
    const float* __restrict__ bk, const float* __restrict__ bq,
    float* __restrict__ Ek, float* __restrict__ Eq) {
  __shared__ __align__(16) unsigned short AhiL[2][2048];
  __shared__ __align__(16) unsigned short AloL[2][2048];
  __shared__ __align__(16) unsigned short BhiL[2][2048];
  __shared__ __align__(16) unsigned short BloL[2][2048];

  const int ct = blockIdx.x;
  int rt = blockIdx.y;
  const float* X;
  const float* bias;
  float* Y;
  int mat;
  if (rt < 64) {
    X = key_ + (size_t)rt * 64 * kH; bias = bk; Y = Ek + (size_t)rt * 64 * kH; mat = 0;
  } else {
    rt -= 64;
    X = query + (size_t)rt * 64 * kH; bias = bq; Y = Eq + (size_t)rt * 64 * kH; mat = 1;
  }

  const int t = threadIdx.x;
  const int ar = t & 63, ag = t >> 6;
  const float* aptr = X + (size_t)ar * kH + ag * 8;
  const unsigned short* bht = Bhi + ((size_t)(mat * 8 + ct) * 16) * 2048 + t * 8;
  const unsigned short* blt = Blo + ((size_t)(mat * 8 + ct) * 16) * 2048 + t * 8;

  float4 pa0, pa1;
  uint4 pbh, pbl;
  auto gload = [&](int kt2) {
    const float* p = aptr + kt2 * 32;
    pa0 = *(const float4*)p;
    pa1 = *(const float4*)(p + 4);
    pbh = *(const uint4*)(bht + (size_t)kt2 * 2048);
    pbl = *(const uint4*)(blt + (size_t)kt2 * 2048);
  };
  auto cwrite = [&](int buf) {
    bf16x8 hv, lv;
#define CVT1(x, e)                                          \
  {                                                         \
    unsigned u = bf16rtn_bits(x);                           \
    float hf = __uint_as_float(u & 0xFFFF0000u);            \
    unsigned v = bf16rtn_bits((x) - hf);                    \
    hv[e] = (short)(u >> 16);                               \
    lv[e] = (short)(v >> 16);                               \
  }
    CVT1(pa0.x, 0) CVT1(pa0.y, 1) CVT1(pa0.z, 2) CVT1(pa0.w, 3)
    CVT1(pa1.x, 4) CVT1(pa1.y, 5) CVT1(pa1.z, 6) CVT1(pa1.w, 7)
#undef CVT1
    *(bf16x8*)&AhiL[buf][t * 8] = hv;
    *(bf16x8*)&AloL[buf][t * 8] = lv;
    *(uint4*)&BhiL[buf][t * 8] = pbh;
    *(uint4*)&BloL[buf][t * 8] = pbl;
  };

  const int l = t & 63, lg = l >> 4, lr = l & 15;
  const int wv = t >> 6, wm = wv >> 1, wn = wv & 1;
  const int oa0 = (lg * 64 + (2 * wm) * 16 + lr) * 8;
  const int ob0 = (lg * 64 + (2 * wn) * 16 + lr) * 8;

  f32x4 acc00 = {0.f, 0.f, 0.f, 0.f};
  f32x4 acc01 = acc00, acc10 = acc00, acc11 = acc00;

  gload(0);
  cwrite(0);
  __syncthreads();

#pragma unroll 2
  for (int kt2 = 0; kt2 < 16; kt2++) {
    if (kt2 < 15) gload(kt2 + 1);

    const unsigned short* Ah = AhiL[kt2 & 1];
    const unsigned short* Al = AloL[kt2 & 1];
    const unsigned short* Bh = BhiL[kt2 & 1];
    const unsigned short* Bl = BloL[kt2 & 1];
    bf16x8 ah0 = *(const bf16x8*)(Ah + oa0);
    bf16x8 ah1 = *(const bf16x8*)(Ah + oa0 + 128);
    bf16x8 al0 = *(const bf16x8*)(Al + oa0);
    bf16x8 al1 = *(const bf16x8*)(Al + oa0 + 128);
    bf16x8 bh0 = *(const bf16x8*)(Bh + ob0);
    bf16x8 bh1 = *(const bf16x8*)(Bh + ob0 + 128);
    bf16x8 bl0 = *(const bf16x8*)(Bl + ob0);
    bf16x8 bl1 = *(const bf16x8*)(Bl + ob0 + 128);

    acc00 = __builtin_amdgcn_mfma_f32_16x16x32_bf16(ah0, bh0, acc00, 0, 0, 0);
    acc01 = __builtin_amdgcn_mfma_f32_16x16x32_bf16(ah0, bh1, acc01, 0, 0, 0);
    acc10 = __builtin_amdgcn_mfma_f32_16x16x32_bf16(ah1, bh0, acc10, 0, 0, 0);
    acc11 = __builtin_amdgcn_mfma_f32_16x16x32_bf16(ah1, bh1, acc11, 0, 0, 0);
    acc00 = __builtin_amdgcn_mfma_f32_16x16x32_bf16(al0, bh0, acc00, 0, 0, 0);
    acc01 = __builtin_amdgcn_mfma_f32_16x16x32_bf16(al0, bh1, acc01, 0, 0, 0);
    acc10 = __builtin_amdgcn_mfma_f32_16x16x32_bf16(al1, bh0, acc10, 0, 0, 0);
    acc11 = __builtin_amdgcn_mfma_f32_16x16x32_bf16(al1, bh1, acc11, 0, 0, 0);
    acc00 = __builtin_amdgcn_mfma_f32_16x16x32_bf16(ah0, bl0, acc00, 0, 0, 0);
    acc01 = __builtin_amdgcn_mfma_f32_16x16x32_bf16(ah0, bl1, acc01, 0, 0, 0);
    acc10 = __builtin_amdgcn_mfma_f32_16x16x32_bf16(ah1, bl0, acc10, 0, 0, 0);
    acc11 = __builtin_amdgcn_mfma_f32_16x16x32_bf16(ah1, bl1, acc11, 0, 0, 0);

    if (kt2 < 15) {
      cwrite((kt2 + 1) & 1);
      __syncthreads();
    }
  }

  // Epilogue: E = exp(2*(acc + bias)). C/D: col = lr, row = lg*4 + jj.
  const int n0 = ct * 64;
  const int col0 = n0 + (2 * wn) * 16 + lr;
  const float b0 = bias[col0];
  const float b1 = bias[col0 + 16];
  const int row0 = (2 * wm) * 16 + lg * 4;
#pragma unroll
  for (int jj = 0; jj < 4; jj++) {
    float* y = Y + (size_t)(row0 + jj) * kH;
    y[col0]      = __expf(2.f * (acc00[jj] + b0));
    y[col0 + 16] = __expf(2.f * (acc01[jj] + b1));
    float* y2 = y + (size_t)16 * kH;
    y2[col0]      = __expf(2.f * (acc10[jj] + b0));
    y2[col0 + 16] = __expf(2.f * (acc11[jj] + b1));
  }
}

// ---------------------------------------------------------------------------
// Scores (raw) -> sout[bq][s], transposed layout: lane = s, loop h.
// score = wsum + sum_h (-2we_h) * rcp(1 + Eq[q][h]*Ek[s][h]), rcps paired:
// w0/a + w1/b = (w0*b + w1*a) * rcp(a*b).
// grid = dim3(8 qt, 16 st, 4 b); block 256 = 4 waves, wave = 2 q x 64 s.
// LDS: Ek chunk [64s][64h] dbuf (XOR-16 swizzled rows), Eq [8][512], wL[512].
// ---------------------------------------------------------------------------
__global__ __launch_bounds__(256) void score_kernel(
    const float* __restrict__ Eq, const float* __restrict__ Ek,
    const float* __restrict__ we, float* __restrict__ sout) {
  __shared__ __align__(16) float EkL[2][64 * 64];
  __shared__ __align__(16) float EqL[8 * 512];
  __shared__ __align__(16) float wL[512];

  const int qt = blockIdx.x, st = blockIdx.y, b = blockIdx.z;
  const int t = threadIdx.x, wv = t >> 6, lane = t & 63;
  const int s0 = st * 64;
  const int q0g = b * kQ + qt * 8;  // global Eq row base for this tile
  const int qA = wv * 2;            // local q pair {qA, qA+1}

  // wsum = sum we (per-wave, identical result in all waves)
  const float4* we4 = (const float4*)(we + lane * 8);
  float4 u0 = we4[0], u1 = we4[1];
  float wsum = u0.x + u0.y + u0.z + u0.w + u1.x + u1.y + u1.z + u1.w;
#pragma unroll
  for (int off = 32; off; off >>= 1) wsum += __shfl_xor(wsum, off);

  // stage wL = -2*we
  if (t < 128) {
    float4 w = ((const float4*)we)[t];
    w.x *= -2.f; w.y *= -2.f; w.z *= -2.f; w.w *= -2.f;
    ((float4*)wL)[t] = w;
  }
  // stage EqL [8][512] (rows q0g..q0g+7 are contiguous in global)
  {
    const float4* src = (const float4*)(Eq + (size_t)q0g * kH);
#pragma unroll
    for (int i = 0; i < 4; i++) {
      int idx = t + 256 * i;
      ((float4*)EqL)[idx] = src[idx];
    }
  }

  // Ek chunk staging: thread t -> row er = t>>4 (+16i), f4-slot ej = t&15.
  // LDS slot swizzle: slot = ej ^ (row & 15) -> lane reads own row conflict-lite.
  const int er = t >> 4;
  const int ej = t & 15;
  const float* ekg = Ek + (size_t)(b * kS + s0 + er) * kH + ej * 4;
  float4 pk[4];
  auto gload = [&](int c) {
#pragma unroll
    for (int i = 0; i < 4; i++)
      pk[i] = *(const float4*)(ekg + (size_t)(16 * i) * kH + c * 64);
  };
  auto lwrite = [&](int buf) {
#pragma unroll
    for (int i = 0; i < 4; i++) {
      const int row = er + 16 * i;
      *(float4*)(&EkL[buf][row * 64 + ((ej ^ (row & 15)) << 2)]) = pk[i];
    }
  };

  gload(0);
  lwrite(0);
  __syncthreads();

  float accA = 0.f, accB = 0.f;
  const int sw = lane & 15;
  const float* eqa = EqL + (qA + 0) * 512;
  const float* eqb = EqL + (qA + 1) * 512;

  for (int c = 0; c < 8; c++) {
    if (c < 7) gload(c + 1);
    const float* ekb = &EkL[c & 1][lane * 64];
    const float* wc = wL + c * 64;
    const float* ea = eqa + c * 64;
    const float* eb = eqb + c * 64;
#pragma unroll 4
    for (int g = 0; g < 16; g++) {
      float4 ek = *(const float4*)(ekb + ((g ^ sw) << 2));
      float4 w = *(const float4*)(wc + g * 4);
      float4 qa = *(const float4*)(ea + g * 4);
      float4 qb = *(const float4*)(eb + g * 4);
      // q = qA: pairs (x,y), (z,w)
      {
        float a1 = fmaf(qa.x, ek.x, 1.f), b1 = fmaf(qa.y, ek.y, 1.f);
        float n1 = fmaf(w.y, a1, w.x * b1);
        accA = fmaf(n1, __builtin_amdgcn_rcpf(a1 * b1), accA);
        float a2 = fmaf(qa.z, ek.z, 1.f), b2 = fmaf(qa.w, ek.w, 1.f);
        float n2 = fmaf(w.w, a2, w.z * b2);
        accA = fmaf(n2, __builtin_amdgcn_rcpf(a2 * b2), accA);
      }
      // q = qA+1
      {
        float a1 = fmaf(qb.x, ek.x, 1.f), b1 = fmaf(qb.y, ek.y, 1.f);
        float n1 = fmaf(w.y, a1, w.x * b1);
        accB = fmaf(n1, __builtin_amdgcn_rcpf(a1 * b1), accB);
        float a2 = fmaf(qb.z, ek.z, 1.f), b2 = fmaf(qb.w, ek.w, 1.f);
        float n2 = fmaf(w.w, a2, w.z * b2);
        accB = fmaf(n2, __builtin_amdgcn_rcpf(a2 * b2), accB);
      }
    }
    if (c < 7) {
      __syncthreads();
      lwrite((c + 1) & 1);
      __syncthreads();
    }
  }

  sout[(size_t)(q0g + qA + 0) * kS + s0 + lane] = accA + wsum;
  sout[(size_t)(q0g + qA + 1) * kS + s0 + lane] = accB + wsum;
}

// ---------------------------------------------------------------------------
// Softmax in place on wout rows of 1024.  grid = 256 rows, 256 thr.
// ---------------------------------------------------------------------------
__global__ __launch_bounds__(256) void softmax_kernel(float* __restrict__ wout) {
  __shared__ float redm[4];
  __shared__ float reds[4];
  const int row = blockIdx.x;
  const int t = threadIdx.x, wave = t >> 6, lane = t & 63;
  float4* rp = (float4*)(wout + (size_t)row * kS);
  float4 v = rp[t];

  float m = fmaxf(fmaxf(v.x, v.y), fmaxf(v.z, v.w));
#pragma unroll
  for (int off = 32; off; off >>= 1) m = fmaxf(m, __shfl_xor(m, off));
  if (lane == 0) redm[wave] = m;
  __syncthreads();
  m = fmaxf(fmaxf(redm[0], redm[1]), fmaxf(redm[2], redm[3]));

  float4 e;
  e.x = __expf(v.x - m); e.y = __expf(v.y - m);
  e.z = __expf(v.z - m); e.w = __expf(v.w - m);
  float sum = e.x + e.y + e.z + e.w;
#pragma unroll
  for (int off = 32; off; off >>= 1) sum += __shfl_xor(sum, off);
  if (lane == 0) reds[wave] = sum;
  __syncthreads();
  sum = reds[0] + reds[1] + reds[2] + reds[3];
  float inv = 1.f / sum;
  e.x *= inv; e.y *= inv; e.z *= inv; e.w *= inv;
  rp[t] = e;
}

// ---------------------------------------------------------------------------
// Context partials: part[sc][bq][h] = sum_{s in chunk} w[bq][s] * value[b][s][h]
// grid = 256 (b x 2 h-chunks x 4 q-chunks x 8 s-chunks), 256 thr.
// ---------------------------------------------------------------------------
__global__ __launch_bounds__(256) void context_kernel(
    const float* __restrict__ wout, const float* __restrict__ value,
    float* __restrict__ part) {
  __shared__ __align__(16) float wt[128][16];
  const int bx = blockIdx.x;
  const int sc = bx & 7, qc = (bx >> 3) & 3, hc = (bx >> 5) & 1, b = bx >> 6;
  const int t = threadIdx.x;
  const int s0 = sc * 128, q0 = qc * 16;

  {
    const int q_l = t & 15;
    const int sseg = (t >> 4) * 8;
    const float4* p4 =
        (const float4*)(wout + (size_t)(b * kQ + q0 + q_l) * kS + s0 + sseg);
    float4 u0 = p4[0], u1 = p4[1];
    wt[sseg + 0][q_l] = u0.x; wt[sseg + 1][q_l] = u0.y;
    wt[sseg + 2][q_l] = u0.z; wt[sseg + 3][q_l] = u0.w;
    wt[sseg + 4][q_l] = u1.x; wt[sseg + 5][q_l] = u1.y;
    wt[sseg + 6][q_l] = u1.z; wt[sseg + 7][q_l] = u1.w;
  }
  __syncthreads();

  const int h = hc * 256 + t;
  const float* vb = value + ((size_t)b * kS + s0) * kH + h;
  float acc[16];
#pragma unroll
  for (int i = 0; i < 16; i++) acc[i] = 0.f;

#pragma unroll 4
  for (int s = 0; s < 128; s++) {
    float v = vb[(size_t)s * kH];
    const float4* wrow = (const float4*)&wt[s][0];
    float4 a0 = wrow[0], a1 = wrow[1], a2 = wrow[2], a3 = wrow[3];
    acc[0]  = fmaf(a0.x, v, acc[0]);  acc[1]  = fmaf(a0.y, v, acc[1]);
    acc[2]  = fmaf(a0.z, v, acc[2]);  acc[3]  = fmaf(a0.w, v, acc[3]);
    acc[4]  = fmaf(a1.x, v, acc[4]);  acc[5]  = fmaf(a1.y, v, acc[5]);
    acc[6]  = fmaf(a1.z, v, acc[6]);  acc[7]  = fmaf(a1.w, v, acc[7]);
    acc[8]  = fmaf(a2.x, v, acc[8]);  acc[9]  = fmaf(a2.y, v, acc[9]);
    acc[10] = fmaf(a2.z, v, acc[10]); acc[11] = fmaf(a2.w, v, acc[11]);
    acc[12] = fmaf(a3.x, v, acc[12]); acc[13] = fmaf(a3.y, v, acc[13]);
    acc[14] = fmaf(a3.z, v, acc[14]); acc[15] = fmaf(a3.w, v, acc[15]);
  }

  float* pp = part + (size_t)sc * kB * kQ * kH;
#pragma unroll
  for (int i = 0; i < 16; i++)
    pp[(size_t)(b * kQ + q0 + i) * kH + h] = acc[i];
}

// ctx[i] = sum over 8 s-chunk partials
__global__ __launch_bounds__(256) void reduce_kernel(
    const float* __restrict__ part, float* __restrict__ ctx) {
  const int i = blockIdx.x * 256 + threadIdx.x;
  float4 a = {0, 0, 0, 0};
#pragma unroll
  for (int p = 0; p < 8; p++) {
    float4 v = ((const float4*)(part + (size_t)p * kB * kQ * kH))[i];
    a.x += v.x; a.y += v.y; a.z += v.z; a.w += v.w;
  }
  ((float4*)ctx)[i] = a;
}

extern "C" void kernel_launch(void* const* d_in, const int* in_sizes, int n_in,
                              void* d_out, int out_size, void* d_ws,
                              size_t ws_size, hipStream_t stream) {
  const float* query = (const float*)d_in[0];
  const float* key_  = (const float*)d_in[1];
  const float* value = (const float*)d_in[2];
  const float* Wq    = (const float*)d_in[3];
  const float* bq    = (const float*)d_in[4];
  const float* Wk    = (const float*)d_in[5];
  const float* bk    = (const float*)d_in[6];
  const float* we    = (const float*)d_in[7];
  // be (d_in[8]) cancels in softmax.

  float* ctx  = (float*)d_out;                         // [256*512]
  float* wout = (float*)d_out + (size_t)kB * kQ * kH;  // [256*1024]

  float* Eq   = (float*)d_ws;                          // 512 KB
  float* Ek   = Eq + (size_t)kB * kQ * kH;             // 8 MB
  float* part = Ek;                                    // aliases Ek (dead after score)
  unsigned short* Bhi =
      (unsigned short*)((char*)d_ws + (size_t)(kB * kQ * kH + kB * kS * kH) * 4);  // +8.5MB
  unsigned short* Blo = Bhi + (size_t)2 * 8 * 16 * 256 * 8;                        // +1MB

  convert_w<<<256, 256, 0, stream>>>(Wk, Wq, Bhi, Blo);
  proj_mfma<<<dim3(8, 68), 256, 0, stream>>>(key_, query, Bhi, Blo, bk, bq, Ek, Eq);
  score_kernel<<<dim3(8, 16, 4), 256, 0, stream>>>(Eq, Ek, we, wout);
  softmax_kernel<<<kB * kQ, 256, 0, stream>>>(wout);
  context_kernel<<<256, 256, 0, stream>>>(wout, value, part);
  reduce_kernel<<<kB * kQ * kH / 4 / 256, 256, 0, stream>>>(part, ctx);
}